// Round 1
// baseline (815.653 us; speedup 1.0000x reference)
//
#include <hip/hip_runtime.h>
#include <cstdint>

#define NN 20000     // nodes
#define NE 640000    // edges
#define NB 128       // basis
#define NG 64        // gaussians
#define NH 256       // hidden
#define NGR 256      // graphs

typedef __attribute__((ext_vector_type(8))) short bf16x8;
typedef __attribute__((ext_vector_type(4))) float f32x4;

__device__ __forceinline__ float bf2f(short s){
  union{ unsigned u; float f; } v; v.u = ((unsigned)(unsigned short)s) << 16; return v.f;
}
__device__ __forceinline__ short f2bf(float f){
  union{ float f; unsigned u; } v; v.f = f;
  unsigned r = v.u + 0x7FFFu + ((v.u >> 16) & 1u);   // RNE
  return (short)(r >> 16);
}
__device__ __forceinline__ bf16x8 mul8(bf16x8 a, bf16x8 b){
  bf16x8 r;
#pragma unroll
  for(int i=0;i<8;i++) r[i] = f2bf(bf2f(a[i]) * bf2f(b[i]));
  return r;
}
__device__ __forceinline__ float tanh_fast(float x){
  x = fminf(8.f, fmaxf(-8.f, x));
  float t = __expf(2.f * x);
  return (t - 1.f) * __builtin_amdgcn_rcpf(t + 1.f);
}

// Stage W[N=NT*16][K=KT*32] as bf16 MFMA B-fragments (B[k][n] = W[n][k]).
// Frag (n,kt): lane holds W[n*16 + (lane&15)][kt*32 + (lane>>4)*8 + j], j=0..7.
// Packed so each lane reads 16B at ((n*KT+kt)*64 + lane)*8 shorts (conflict-free b128).
template<int NT, int KT>
__device__ __forceinline__ void stage_w(const float* __restrict__ W, short* lds){
  const int total = NT*KT*64;
  for(int c = (int)threadIdx.x; c < total; c += 256){
    int lane = c & 63;
    int kt = (c >> 6) % KT;
    int n  = c / (64*KT);
    int row = n*16 + (lane & 15);
    int col = kt*32 + (lane >> 4)*8;
    const float* p = W + (size_t)row*(KT*32) + col;
    short* d = lds + (size_t)c*8;
#pragma unroll
    for(int j=0;j<8;j++) d[j] = f2bf(p[j]);
  }
}

// ---------------- CSR build ----------------
__global__ void k_embed(const int* __restrict__ Z, const float* __restrict__ E, float* __restrict__ C){
  int i = blockIdx.x*256 + threadIdx.x;            // over NN*32 float4
  if(i >= NN*32) return;
  int node = i >> 5, k4 = i & 31;
  ((float4*)C)[i] = ((const float4*)(E + (size_t)Z[node]*NB))[k4];
}

__global__ void k_hist(const int* __restrict__ dst, int* __restrict__ cnt){
  int e = blockIdx.x*256 + threadIdx.x;
  if(e < NE) atomicAdd(&cnt[dst[e]], 1);
}

__global__ __launch_bounds__(1024) void k_scan(const int* __restrict__ cnt, int* __restrict__ cur){
  __shared__ int lds[1024];
  const int t = threadIdx.x;
  const int base = t*20;
  int loc[20]; int s = 0;
#pragma unroll
  for(int j=0;j<20;j++){ int i = base+j; int c = (i<NN)? cnt[i] : 0; loc[j] = s; s += c; }
  lds[t] = s;
  __syncthreads();
  for(int off=1; off<1024; off<<=1){
    int v = (t >= off) ? lds[t-off] : 0;
    __syncthreads();
    lds[t] += v;
    __syncthreads();
  }
  int prefix = (t > 0) ? lds[t-1] : 0;
#pragma unroll
  for(int j=0;j<20;j++){ int i = base+j; if(i<NN) cur[i] = prefix + loc[j]; }
}

__global__ void k_fill(const int* __restrict__ src, const int* __restrict__ dst,
                       int* __restrict__ cur, int* __restrict__ perm,
                       int* __restrict__ srcv, int* __restrict__ dstv){
  int e = blockIdx.x*256 + threadIdx.x;
  if(e < NE){
    int v = dst[e];
    int p = atomicAdd(&cur[v], 1);
    perm[p] = e;
    srcv[p] = src[e];
    dstv[p] = v;
  }
}

// ---------------- d_feat = edge_attr[perm] @ dfW.T + dfb  (bf16, perm order) ----------------
__global__ __launch_bounds__(256,2) void k_dprep(
  const float* __restrict__ ea, const int* __restrict__ perm,
  const float* __restrict__ dfW, const float* __restrict__ dfb, short* __restrict__ dft)
{
  __shared__ short ldsW[8*2*64*8];   // 16 KB
  stage_w<8,2>(dfW, ldsW);
  __syncthreads();
  const int lane = threadIdx.x & 63, wave = threadIdx.x >> 6;
  const int quad = lane>>4, lc = lane&15;
  const int base = (blockIdx.x*4 + wave)*32;
  bf16x8 a[2][2];
#pragma unroll
  for(int mt=0;mt<2;mt++){
    int idx = base + mt*16 + lc;
    int e = perm[idx];
    const float* p = ea + (size_t)e*NG;
#pragma unroll
    for(int kt=0;kt<2;kt++){
      const float* q = p + kt*32 + quad*8;
      bf16x8 t;
#pragma unroll
      for(int j=0;j<8;j++) t[j] = f2bf(q[j]);
      a[mt][kt] = t;
    }
  }
  f32x4 acc[2][8];
  f32x4 z = {0.f,0.f,0.f,0.f};
#pragma unroll
  for(int mt=0;mt<2;mt++)
#pragma unroll
    for(int n2=0;n2<8;n2++) acc[mt][n2] = z;
#pragma unroll
  for(int kt=0;kt<2;kt++)
#pragma unroll
    for(int n2=0;n2<8;n2++){
      bf16x8 b = *(const bf16x8*)(ldsW + ((size_t)(n2*2+kt)*64 + lane)*8);
      acc[0][n2] = __builtin_amdgcn_mfma_f32_16x16x32_bf16(a[0][kt], b, acc[0][n2], 0, 0, 0);
      acc[1][n2] = __builtin_amdgcn_mfma_f32_16x16x32_bf16(a[1][kt], b, acc[1][n2], 0, 0, 0);
    }
#pragma unroll
  for(int n2=0;n2<8;n2++){
    float bias = dfb[n2*16 + lc];
#pragma unroll
    for(int mt=0;mt<2;mt++)
#pragma unroll
      for(int r=0;r<4;r++)
        dft[(size_t)(base + mt*16 + quad*4 + r)*NB + n2*16 + lc] = f2bf(acc[mt][n2][r] + bias);
  }
}

// ---------------- cfC = bf16(C @ cfW.T + cfb) on nodes ----------------
__global__ __launch_bounds__(256,2) void k_cf(
  const float* __restrict__ C, const float* __restrict__ cfW,
  const float* __restrict__ cfb, short* __restrict__ cfC)
{
  __shared__ short ldsW[8*4*64*8];   // 32 KB
  stage_w<8,4>(cfW, ldsW);
  __syncthreads();
  const int lane = threadIdx.x & 63, wave = threadIdx.x >> 6;
  const int quad = lane>>4, lc = lane&15;
  const int base = (blockIdx.x*4 + wave)*32;
  if(base >= NN) return;
  bf16x8 a[2][4];
#pragma unroll
  for(int mt=0;mt<2;mt++){
    int node = base + mt*16 + lc; if(node > NN-1) node = NN-1;
    const float* p = C + (size_t)node*NB;
#pragma unroll
    for(int kt=0;kt<4;kt++){
      const float* q = p + kt*32 + quad*8;
      bf16x8 t;
#pragma unroll
      for(int j=0;j<8;j++) t[j] = f2bf(q[j]);
      a[mt][kt] = t;
    }
  }
  f32x4 acc[2][8];
  f32x4 z = {0.f,0.f,0.f,0.f};
#pragma unroll
  for(int mt=0;mt<2;mt++)
#pragma unroll
    for(int n2=0;n2<8;n2++) acc[mt][n2] = z;
#pragma unroll
  for(int kt=0;kt<4;kt++)
#pragma unroll
    for(int n2=0;n2<8;n2++){
      bf16x8 b = *(const bf16x8*)(ldsW + ((size_t)(n2*4+kt)*64 + lane)*8);
      acc[0][n2] = __builtin_amdgcn_mfma_f32_16x16x32_bf16(a[0][kt], b, acc[0][n2], 0, 0, 0);
      acc[1][n2] = __builtin_amdgcn_mfma_f32_16x16x32_bf16(a[1][kt], b, acc[1][n2], 0, 0, 0);
    }
#pragma unroll
  for(int n2=0;n2<8;n2++){
    float bias = cfb[n2*16 + lc];
#pragma unroll
    for(int mt=0;mt<2;mt++)
#pragma unroll
      for(int r=0;r<4;r++){
        int node = base + mt*16 + quad*4 + r;
        if(node < NN) cfC[(size_t)node*NB + n2*16 + lc] = f2bf(acc[mt][n2][r] + bias);
      }
  }
}

// ---------------- edge kernel: m = tanh((cfC[src] * dft) @ fcW.T), segmented scatter ----------------
__global__ __launch_bounds__(256,2) void k_edge(
    const short* __restrict__ cfC, const short* __restrict__ dft,
    const int* __restrict__ srcv, const int* __restrict__ dstv,
    const float* __restrict__ fcW, float* __restrict__ Cout)
{
  __shared__ short ldsW[8*4*64*8];   // 32 KB
  stage_w<8,4>(fcW, ldsW);
  __syncthreads();
  const int lane = threadIdx.x & 63, wave = threadIdx.x >> 6;
  const int quad = lane>>4, lc = lane&15;
  const int tile0 = (blockIdx.x*4 + wave)*2;
#pragma unroll 1
  for(int s = 0; s < 2; s++){
    const int base = (tile0 + s)*32;
    // A2 fragments: (cfC[src] * d_feat), gathered directly in A layout
    bf16x8 a2[2][4];
#pragma unroll
    for(int mt=0; mt<2; mt++){
      const int e = base + mt*16 + lc;
      const short* cp = cfC + (size_t)srcv[e]*NB;
      const short* ddp = dft + (size_t)e*NB;
#pragma unroll
      for(int kt=0; kt<4; kt++){
        bf16x8 c8 = *(const bf16x8*)(cp + kt*32 + quad*8);
        bf16x8 d8 = *(const bf16x8*)(ddp + kt*32 + quad*8);
        a2[mt][kt] = mul8(c8, d8);
      }
    }
    f32x4 acc[2][8];
    f32x4 z = {0.f,0.f,0.f,0.f};
#pragma unroll
    for(int mt=0;mt<2;mt++)
#pragma unroll
      for(int n2=0;n2<8;n2++) acc[mt][n2] = z;
#pragma unroll
    for(int kt=0; kt<4; kt++){
#pragma unroll
      for(int n2=0; n2<8; n2++){
        bf16x8 b = *(const bf16x8*)(ldsW + ((size_t)(n2*4 + kt)*64 + lane)*8);
        acc[0][n2] = __builtin_amdgcn_mfma_f32_16x16x32_bf16(a2[0][kt], b, acc[0][n2], 0, 0, 0);
        acc[1][n2] = __builtin_amdgcn_mfma_f32_16x16x32_bf16(a2[1][kt], b, acc[1][n2], 0, 0, 0);
      }
    }
#pragma unroll
    for(int mt=0;mt<2;mt++)
#pragma unroll
      for(int n2=0;n2<8;n2++)
#pragma unroll
        for(int r=0;r<4;r++) acc[mt][n2][r] = tanh_fast(acc[mt][n2][r]);

    // segmented reduction over dst (perm-sorted) + sparse atomics
    const int i = lane & 31;
    const int di = dstv[base + i];
    const int dprev = (i > 0) ? dstv[base + i - 1] : -1;
    unsigned long long mm = __ballot(di != dprev) & 0xFFFFFFFFull;
    while(mm){
      int lo = __ffsll(mm) - 1;
      mm &= mm - 1;
      int hi = mm ? (__ffsll(mm) - 1) : 32;
      int v = __shfl(di, lo);
      float sums[8];
#pragma unroll
      for(int n2=0;n2<8;n2++) sums[n2] = 0.f;
#pragma unroll
      for(int mt=0; mt<2; mt++)
#pragma unroll
        for(int r=0; r<4; r++){
          int e = mt*16 + quad*4 + r;
          float sel = (e >= lo && e < hi) ? 1.f : 0.f;
#pragma unroll
          for(int n2=0;n2<8;n2++) sums[n2] = fmaf(acc[mt][n2][r], sel, sums[n2]);
        }
#pragma unroll
      for(int n2=0;n2<8;n2++){
        float x = sums[n2];
        x += __shfl_xor(x, 16);
        x += __shfl_xor(x, 32);
        if(quad == 0) atomicAdd(&Cout[(size_t)v*NB + n2*16 + lc], x);
      }
    }
  }
}

// ---------------- readout: out += pool(tanh(C@r1W.T + r1b)@r2W.T + r2b) ----------------
__global__ __launch_bounds__(256,2) void k_readout(
  const float* __restrict__ C, const float* __restrict__ r1W, const float* __restrict__ r1b,
  const float* __restrict__ r2W, const float* __restrict__ r2b,
  const int* __restrict__ batch, float* __restrict__ out)
{
  __shared__ short ldsW[16*4*64*8];  // 64 KB
  stage_w<16,4>(r1W, ldsW);
  __syncthreads();
  const int lane = threadIdx.x & 63, wave = threadIdx.x >> 6;
  const int quad = lane>>4, lc = lane&15;
  const int base = (blockIdx.x*4 + wave)*16;
  if(base >= NN) return;
  int node = base + lc; if(node > NN-1) node = NN-1;
  bf16x8 a[4];
  const float* p = C + (size_t)node*NB;
#pragma unroll
  for(int kt=0;kt<4;kt++){
    const float* q = p + kt*32 + quad*8;
    bf16x8 t;
#pragma unroll
    for(int j=0;j<8;j++) t[j] = f2bf(q[j]);
    a[kt] = t;
  }
  f32x4 acc[16];
  f32x4 z = {0.f,0.f,0.f,0.f};
#pragma unroll
  for(int nt=0;nt<16;nt++) acc[nt] = z;
#pragma unroll
  for(int kt=0;kt<4;kt++)
#pragma unroll
    for(int nt=0;nt<16;nt++){
      bf16x8 b = *(const bf16x8*)(ldsW + ((size_t)(nt*4+kt)*64 + lane)*8);
      acc[nt] = __builtin_amdgcn_mfma_f32_16x16x32_bf16(a[kt], b, acc[nt], 0, 0, 0);
    }
#pragma unroll
  for(int nt=0;nt<16;nt++){
    float bias = r1b[nt*16 + lc];
#pragma unroll
    for(int r=0;r<4;r++) acc[nt][r] = tanh_fast(acc[nt][r] + bias);
  }
#pragma unroll
  for(int r=0;r<4;r++){
    int nd = base + quad*4 + r;
#pragma unroll
    for(int o=0;o<4;o++){
      float ps = 0.f;
#pragma unroll
      for(int nt=0;nt<16;nt++) ps = fmaf(acc[nt][r], r2W[(size_t)o*NH + nt*16 + lc], ps);
      ps += __shfl_xor(ps, 1);
      ps += __shfl_xor(ps, 2);
      ps += __shfl_xor(ps, 4);
      ps += __shfl_xor(ps, 8);
      if(lc == 0 && nd < NN) atomicAdd(&out[batch[nd]*4 + o], ps + r2b[o]);
    }
  }
}

extern "C" void kernel_launch(void* const* d_in, const int* in_sizes, int n_in,
                              void* d_out, int out_size, void* d_ws, size_t ws_size,
                              hipStream_t stream) {
  const int*   Z      = (const int*)d_in[0];
  const int*   ei     = (const int*)d_in[1];
  const float* ea     = (const float*)d_in[2];
  const int*   batch  = (const int*)d_in[3];
  const float* embedW = (const float*)d_in[4];
  const float* cfW    = (const float*)d_in[5];
  const float* cfb    = (const float*)d_in[6];
  const float* dfW    = (const float*)d_in[7];
  const float* dfb    = (const float*)d_in[8];
  const float* fcW    = (const float*)d_in[9];
  const float* r1W    = (const float*)d_in[10];
  const float* r1b    = (const float*)d_in[11];
  const float* r2W    = (const float*)d_in[12];
  const float* r2b    = (const float*)d_in[13];
  const int* src = ei;
  const int* dst = ei + NE;

  char* p = (char*)d_ws;
  auto alloc = [&](size_t b){ char* r = p; p += (b + 255) & ~(size_t)255; return r; };
  float* CA    = (float*)alloc((size_t)NN*NB*4);
  float* CB    = (float*)alloc((size_t)NN*NB*4);
  short* cfC   = (short*)alloc((size_t)NN*NB*2);
  short* dft   = (short*)alloc((size_t)NE*NB*2);
  int*   cnt   = (int*)alloc((size_t)NN*4);
  int*   cursor= (int*)alloc((size_t)NN*4);
  int*   perm  = (int*)alloc((size_t)NE*4);
  int*   srcv  = (int*)alloc((size_t)NE*4);
  int*   dstv  = (int*)alloc((size_t)NE*4);
  size_t needed = (size_t)(p - (char*)d_ws);

  hipMemsetAsync(d_out, 0, (size_t)out_size*sizeof(float), stream);
  if(needed > ws_size) return;   // ws too small -> all-zero output as a diagnostic signature

  hipMemsetAsync(cnt, 0, (size_t)NN*4, stream);
  k_embed<<<2500, 256, 0, stream>>>(Z, embedW, CA);
  k_hist <<<2500, 256, 0, stream>>>(dst, cnt);
  k_scan <<<1, 1024, 0, stream>>>(cnt, cursor);
  k_fill <<<2500, 256, 0, stream>>>(src, dst, cursor, perm, srcv, dstv);
  k_dprep<<<5000, 256, 0, stream>>>(ea, perm, dfW, dfb, dft);

  float* cur = CA; float* nxt = CB;
  for(int it = 0; it < 3; it++){
    k_cf<<<157, 256, 0, stream>>>(cur, cfW, cfb, cfC);
    hipMemcpyAsync(nxt, cur, (size_t)NN*NB*4, hipMemcpyDeviceToDevice, stream);
    k_edge<<<2500, 256, 0, stream>>>(cfC, dft, srcv, dstv, fcW, nxt);
    float* t = cur; cur = nxt; nxt = t;
  }
  k_readout<<<313, 256, 0, stream>>>(cur, r1W, r1b, r2W, r2b, batch, (float*)d_out);
}